// Round 2
// baseline (73.228 us; speedup 1.0000x reference)
//
#include <hip/hip_runtime.h>

// 3x3 cross-correlation, padding=1, NCHW fp32.
// out[b,o,h,w] = bias[o] + sum_{ky,kx,c} comb[o,(ky*3+kx)*16+c] * x[b,c,h+ky-1,w+kx-1]
// B=4, C=16, O=16, H=450, W=480.
//
// Round 2: occupancy fix. R1 had 3375 waves vs 8192 slots (grid-limited,
// OccupancyPercent=25, VALUBusy=46). Split outputs across 2 threads:
// each thread computes 4 consecutive w pixels x 8 output channels.
// 432k threads = 6750 waves = 82% of slots. o-group in tid bit 0 so
// paired lanes load identical x addresses (merged by coalescer).

#define HH 450
#define WW 480
#define BB 4
#define CC 16
#define OO 16
#define WQ (WW / 4)                  // 120 quads per row
#define NT2 (BB * HH * WQ * 2)       // 432000 threads (2 o-groups)

__global__ __launch_bounds__(256) void flow_conv_kernel(
    const float* __restrict__ x, const float* __restrict__ comb,
    const float* __restrict__ bias, float* __restrict__ out)
{
    __shared__ __align__(16) float wlds[3 * CC * 3 * OO]; // [ky][c][kx][o] = 2304 floats

    // Stage + repack weights: wlds[((ky*16+c)*3+kx)*16+o] = comb[o*144 + (ky*3+kx)*16 + c]
    for (int idx = threadIdx.x; idx < 3 * CC * 3 * OO; idx += 256) {
        int o    = idx & 15;
        int kx   = (idx >> 4) % 3;
        int rest = idx / 48;          // ky*16 + c
        int c    = rest & 15;
        int ky   = rest >> 4;
        wlds[idx] = comb[o * 144 + (ky * 3 + kx) * CC + c];
    }
    __syncthreads();

    int tid = blockIdx.x * 256 + threadIdx.x;
    if (tid >= NT2) return;

    int og   = tid & 1;               // output group: o in [og*8, og*8+8)
    int rest = tid >> 1;
    int wq = rest % WQ;
    int t2 = rest / WQ;
    int h  = t2 % HH;
    int b  = t2 / HH;
    int w  = wq * 4;

    float acc[8][4];
    #pragma unroll
    for (int o = 0; o < 8; ++o) {
        float bv = bias[og * 8 + o];
        acc[o][0] = bv; acc[o][1] = bv; acc[o][2] = bv; acc[o][3] = bv;
    }

    const float* xb = x + (size_t)b * CC * HH * WW;

    #pragma unroll 1
    for (int ky = 0; ky < 3; ++ky) {
        int hy = h + ky - 1;
        bool hok = (unsigned)hy < (unsigned)HH;
        const float* xrow = xb + (size_t)hy * WW + w;

        #pragma unroll 1
        for (int c = 0; c < CC; ++c) {
            // xv[j] = x[b,c,hy, w + j - 1], zero-padded
            float xv[6];
            if (hok) {
                const float* rp = xrow + (size_t)c * (HH * WW);
                float4 m = *(const float4*)rp;          // w .. w+3 (16B aligned)
                xv[0] = (w > 0)      ? rp[-1] : 0.0f;
                xv[1] = m.x; xv[2] = m.y; xv[3] = m.z; xv[4] = m.w;
                xv[5] = (w < WW - 4) ? rp[4]  : 0.0f;
            } else {
                #pragma unroll
                for (int j = 0; j < 6; ++j) xv[j] = 0.0f;
            }

            const float4* w4 = (const float4*)&wlds[(ky * CC + c) * 48];
            #pragma unroll
            for (int kx = 0; kx < 3; ++kx) {
                #pragma unroll
                for (int oq = 0; oq < 2; ++oq) {
                    float4 wv = w4[kx * 4 + og * 2 + oq];
                    float wf[4] = {wv.x, wv.y, wv.z, wv.w};
                    #pragma unroll
                    for (int j = 0; j < 4; ++j) {
                        int o = oq * 4 + j;
                        #pragma unroll
                        for (int p = 0; p < 4; ++p)
                            acc[o][p] = fmaf(wf[j], xv[p + kx], acc[o][p]);
                    }
                }
            }
        }
    }

    float* ob = out + (size_t)b * OO * HH * WW + (size_t)(og * 8) * (HH * WW)
                    + (size_t)h * WW + w;
    #pragma unroll
    for (int o = 0; o < 8; ++o) {
        float4 st = make_float4(acc[o][0], acc[o][1], acc[o][2], acc[o][3]);
        *(float4*)(ob + (size_t)o * (HH * WW)) = st;
    }
}

extern "C" void kernel_launch(void* const* d_in, const int* in_sizes, int n_in,
                              void* d_out, int out_size, void* d_ws, size_t ws_size,
                              hipStream_t stream) {
    const float* x    = (const float*)d_in[0];
    const float* comb = (const float*)d_in[1];
    const float* bias = (const float*)d_in[2];
    float* out        = (float*)d_out;

    int nblocks = (NT2 + 255) / 256;  // 1688
    flow_conv_kernel<<<nblocks, 256, 0, stream>>>(x, comb, bias, out);
}

// Round 3
// 44.863 us; speedup vs baseline: 1.6323x; 1.6323x over previous
//
#include <hip/hip_runtime.h>

// 3x3 cross-correlation, padding=1, NCHW, fp32 in/out, bf16 MFMA compute.
// out[b,o,h,w] = bias[o] + sum_{i,c} comb[o, i*16+c] * x[b,c,h+dy_i,w+dx_i]
// B=4, C=16, O=16, H=450, W=480. K = 144 = 9 flows x 16 c, padded to 5x32.
//
// Round 3: MFMA. fp32-VALU path floors at ~25us; memory floor is ~18us.
// Per block: (b, h, 240-pixel half-row). Stage 3 x-rows x 16c x 244wi as
// bf16 in LDS [ky][wi][c], 48B/wi row (16B-aligned b128 reads, 12-bank
// stride = conflict-free). kx shifts = offset reads of same staged rows.
// 5x mfma_f32_16x16x32_bf16 per 16-pixel tile, A-frags in registers.

#define HH 450
#define WW 480
#define BB 4
#define CC 16
#define OO 16
#define WT   240                 // pixels per block
#define WIN  244                 // staged wi count (w0-1 .. w0+242)
#define ROWS 24                  // shorts per wi row (16 c + 8 pad = 48B)
#define NTILE 15                 // 16-pixel MFMA tiles per block

typedef __attribute__((ext_vector_type(8))) short   bf16x8;
typedef __attribute__((ext_vector_type(4))) float   f32x4;
typedef __attribute__((ext_vector_type(8))) unsigned short u16x8;

static __device__ __forceinline__ unsigned short f2bf(float f) {
    unsigned u = __builtin_bit_cast(unsigned, f);
    u = u + 0x7FFFu + ((u >> 16) & 1u);   // RNE (inputs are finite normals)
    return (unsigned short)(u >> 16);
}

__global__ __launch_bounds__(256, 4) void flow_mfma_kernel(
    const float* __restrict__ x, const float* __restrict__ comb,
    const float* __restrict__ bias, float* __restrict__ out)
{
    __shared__ __align__(16) short xs[3 * WIN * ROWS];  // 35136 B

    const int tid  = threadIdx.x;
    const int lane = tid & 63;
    const int wv   = tid >> 6;

    // ---- block decode: blk = ((b*450) + h)*2 + half ----
    int blk  = blockIdx.x;
    int half = blk & 1;
    int t2   = blk >> 1;
    int h    = t2 % HH;
    int b    = t2 / HH;
    int w0   = half * WT;

    // ---- A-frags: weights, converted fp32->bf16 once, held in VGPRs ----
    const int col = lane & 15;          // pixel-in-tile / output row o
    const int grp = lane >> 4;          // 0..3
    const int o   = col;
    bf16x8 af[5];
    #pragma unroll
    for (int m = 0; m < 5; ++m) {
        int k0 = m * 32 + grp * 8;
        bf16x8 a;
        if (k0 < 144) {
            float4 u = *(const float4*)(comb + o * 144 + k0);
            float4 v = *(const float4*)(comb + o * 144 + k0 + 4);
            a[0] = (short)f2bf(u.x); a[1] = (short)f2bf(u.y);
            a[2] = (short)f2bf(u.z); a[3] = (short)f2bf(u.w);
            a[4] = (short)f2bf(v.x); a[5] = (short)f2bf(v.y);
            a[6] = (short)f2bf(v.z); a[7] = (short)f2bf(v.w);
        } else {
            #pragma unroll
            for (int j = 0; j < 8; ++j) a[j] = 0;
        }
        af[m] = a;
    }
    f32x4 bv = *(const f32x4*)(bias + grp * 4);   // acc init: bias[grp*4+r]

    // ---- stage x -> LDS bf16, layout xs[ky][wi][c], 48B per wi row ----
    // item s: ch = s&1 (c half), wi = (s>>1)%WIN, ky = (s>>1)/WIN
    const int ITEMS = 3 * WIN * 2;   // 1464
    for (int s = tid; s < ITEMS; s += 256) {
        int ch = s & 1;
        int r  = s >> 1;
        int wi = r % WIN;
        int ky = r / WIN;
        int hy = h + ky - 1;
        int w  = w0 + wi - 1;
        u16x8 v8;
        if (((unsigned)hy < (unsigned)HH) && ((unsigned)w < (unsigned)WW)) {
            const float* xp = x + (((size_t)(b * CC + ch * 8) * HH + hy) * WW + w);
            #pragma unroll
            for (int j = 0; j < 8; ++j)
                v8[j] = f2bf(xp[(size_t)j * HH * WW]);
        } else {
            #pragma unroll
            for (int j = 0; j < 8; ++j) v8[j] = 0;
        }
        *(u16x8*)(&xs[(ky * WIN + wi) * ROWS + ch * 8]) = v8;
    }
    __syncthreads();

    // ---- per-lane B-frag base offsets (short-index) ----
    // chunk m<4: flows i = 2m + fo, fo = grp>>1, k-half ch = grp&1
    // B[k][n]: lane n = col, k = grp*8+j -> xs[ky_i][n0+col+kx_i][ch*8..+8]
    const int fo = grp >> 1;
    const int ch = grp & 1;
    int boff[5];
    #pragma unroll
    for (int m = 0; m < 4; ++m) {
        int i  = 2 * m + fo;
        int ky = i / 3;
        int kx = i % 3;
        boff[m] = ((ky * WIN) + col + kx) * ROWS + ch * 8;
    }
    boff[4] = ((2 * WIN) + col + 2) * ROWS + ch * 8;   // flow 8 (ky=2,kx=2)

    // ---- compute: tiles t = wv, wv+4, ... ----
    for (int t = wv; t < NTILE; t += 4) {
        int n0 = t * 16;
        f32x4 acc = bv;
        #pragma unroll
        for (int m = 0; m < 4; ++m) {
            bf16x8 bf = *(const bf16x8*)(&xs[boff[m] + n0 * ROWS]);
            acc = __builtin_amdgcn_mfma_f32_16x16x32_bf16(af[m], bf, acc, 0, 0, 0);
        }
        bf16x8 b4;
        if (grp < 2) {
            b4 = *(const bf16x8*)(&xs[boff[4] + n0 * ROWS]);
        } else {
            #pragma unroll
            for (int j = 0; j < 8; ++j) b4[j] = 0;
        }
        acc = __builtin_amdgcn_mfma_f32_16x16x32_bf16(af[4], b4, acc, 0, 0, 0);

        // D: col = lane&15 (pixel), row o = grp*4 + r
        float* op = out + (((size_t)(b * OO + grp * 4) * HH + h) * WW + w0 + n0 + col);
        #pragma unroll
        for (int r = 0; r < 4; ++r)
            op[(size_t)r * HH * WW] = acc[r];
    }
}

extern "C" void kernel_launch(void* const* d_in, const int* in_sizes, int n_in,
                              void* d_out, int out_size, void* d_ws, size_t ws_size,
                              hipStream_t stream) {
    const float* x    = (const float*)d_in[0];
    const float* comb = (const float*)d_in[1];
    const float* bias = (const float*)d_in[2];
    float* out        = (float*)d_out;

    int nblocks = BB * HH * 2;   // 3600
    flow_mfma_kernel<<<nblocks, 256, 0, stream>>>(x, comb, bias, out);
}

// Round 4
// 43.372 us; speedup vs baseline: 1.6884x; 1.0344x over previous
//
#include <hip/hip_runtime.h>

// 3x3 cross-correlation, padding=1, NCHW, fp32 in/out, bf16 MFMA compute.
// out[b,o,h,w] = bias[o] + sum_{i,c} comb[o, i*16+c] * x[b,c,h+dy_i,w+dx_i]
// B=4, C=16, O=16, H=450, W=480. K = 144 = 9 flows x 16 c, padded to 5x32.
//
// Round 4 (from R3 counters: VALUBusy dominated by software f2bf; 1.63M LDS
// bank conflicts from 48B row stride):
//  - v_cvt_pk_bf16_f32: 1 inst per 2 floats (was ~4-5 ops/element RNE)
//  - LDS split per c-half: xs[ch][ky*WIN+wi][8] -> 16B rows, consecutive
//    lanes hit consecutive 16B = conflict-free for b128 read AND write
//  - LDS 35.3 -> 23.4 KB, __launch_bounds__(256,6) -> 6 blocks/CU

#define HH 450
#define WW 480
#define BB 4
#define CC 16
#define OO 16
#define WT   240                 // pixels per block
#define WIN  244                 // staged wi count (w0-1 .. w0+242)
#define NTILE 15                 // 16-pixel MFMA tiles per block

typedef __attribute__((ext_vector_type(8))) short    bf16x8;
typedef __attribute__((ext_vector_type(4))) float    f32x4;
typedef __attribute__((ext_vector_type(4))) unsigned u32x4;

static __device__ __forceinline__ unsigned cvt_pk_bf16(float a, float b) {
    unsigned r;
    asm("v_cvt_pk_bf16_f32 %0, %1, %2" : "=v"(r) : "v"(a), "v"(b));
    return r;   // lo16 = bf16(a), hi16 = bf16(b), RNE
}

__global__ __launch_bounds__(256, 6) void flow_mfma_kernel(
    const float* __restrict__ x, const float* __restrict__ comb,
    const float* __restrict__ bias, float* __restrict__ out)
{
    // [c-half][ky*WIN + wi][8 shorts] : 16B rows, 23424 B total
    __shared__ __align__(16) short xs[2][3 * WIN][8];

    const int tid  = threadIdx.x;
    const int lane = tid & 63;
    const int wv   = tid >> 6;

    // ---- block decode: blk = ((b*450) + h)*2 + half ----
    int blk  = blockIdx.x;
    int half = blk & 1;
    int t2   = blk >> 1;
    int h    = t2 % HH;
    int b    = t2 / HH;
    int w0   = half * WT;

    // ---- A-frags: weights fp32->bf16 once, in VGPRs ----
    const int col = lane & 15;          // pixel-in-tile (B col) / output o (A row)
    const int grp = lane >> 4;          // 0..3
    bf16x8 af[5];
    #pragma unroll
    for (int m = 0; m < 5; ++m) {
        int k0 = m * 32 + grp * 8;
        u32x4 p;
        if (k0 < 144) {
            float4 u = *(const float4*)(comb + col * 144 + k0);
            float4 v = *(const float4*)(comb + col * 144 + k0 + 4);
            p[0] = cvt_pk_bf16(u.x, u.y);
            p[1] = cvt_pk_bf16(u.z, u.w);
            p[2] = cvt_pk_bf16(v.x, v.y);
            p[3] = cvt_pk_bf16(v.z, v.w);
        } else {
            p[0] = p[1] = p[2] = p[3] = 0u;
        }
        af[m] = __builtin_bit_cast(bf16x8, p);
    }
    f32x4 bv = *(const f32x4*)(bias + grp * 4);   // acc init: bias[grp*4+r]

    // ---- stage x -> LDS bf16 ----
    // item s: ch = s&1, r = s>>1 = ky*WIN + wi
    const int ITEMS = 3 * WIN * 2;   // 1464
    for (int s = tid; s < ITEMS; s += 256) {
        int ch = s & 1;
        int r  = s >> 1;
        int wi = r % WIN;
        int ky = r / WIN;
        int hy = h + ky - 1;
        int w  = w0 + wi - 1;
        u32x4 p;
        if (((unsigned)hy < (unsigned)HH) && ((unsigned)w < (unsigned)WW)) {
            const float* xp = x + (((size_t)(b * CC + ch * 8) * HH + hy) * WW + w);
            float f0 = xp[0];
            float f1 = xp[(size_t)1 * HH * WW];
            float f2 = xp[(size_t)2 * HH * WW];
            float f3 = xp[(size_t)3 * HH * WW];
            float f4 = xp[(size_t)4 * HH * WW];
            float f5 = xp[(size_t)5 * HH * WW];
            float f6 = xp[(size_t)6 * HH * WW];
            float f7 = xp[(size_t)7 * HH * WW];
            p[0] = cvt_pk_bf16(f0, f1);
            p[1] = cvt_pk_bf16(f2, f3);
            p[2] = cvt_pk_bf16(f4, f5);
            p[3] = cvt_pk_bf16(f6, f7);
        } else {
            p[0] = p[1] = p[2] = p[3] = 0u;
        }
        *(u32x4*)(&xs[ch][r][0]) = p;
    }
    __syncthreads();

    // ---- per-lane B-frag row offsets (in 16B rows within xs[ch]) ----
    // chunk m<4: flow i = 2m + (grp>>1), c-half ch = grp&1
    const int fo = grp >> 1;
    const int ch = grp & 1;
    int boff[5];
    #pragma unroll
    for (int m = 0; m < 4; ++m) {
        int i  = 2 * m + fo;
        int ky = i / 3;
        int kx = i % 3;
        boff[m] = ky * WIN + col + kx;
    }
    boff[4] = 2 * WIN + col + 2;        // flow 8 (ky=2, kx=2)

    // ---- compute: tiles t = wv, wv+4, ... ----
    for (int t = wv; t < NTILE; t += 4) {
        int n0 = t * 16;
        f32x4 acc = bv;
        #pragma unroll
        for (int m = 0; m < 4; ++m) {
            bf16x8 bf = *(const bf16x8*)(&xs[ch][boff[m] + n0][0]);
            acc = __builtin_amdgcn_mfma_f32_16x16x32_bf16(af[m], bf, acc, 0, 0, 0);
        }
        bf16x8 b4;
        if (grp < 2) {
            b4 = *(const bf16x8*)(&xs[ch][boff[4] + n0][0]);
        } else {
            #pragma unroll
            for (int j = 0; j < 8; ++j) b4[j] = 0;
        }
        acc = __builtin_amdgcn_mfma_f32_16x16x32_bf16(af[4], b4, acc, 0, 0, 0);

        // D: col = pixel, row o = grp*4 + r
        float* op = out + (((size_t)(b * OO + grp * 4) * HH + h) * WW + w0 + n0 + col);
        #pragma unroll
        for (int r = 0; r < 4; ++r)
            op[(size_t)r * HH * WW] = acc[r];
    }
}

extern "C" void kernel_launch(void* const* d_in, const int* in_sizes, int n_in,
                              void* d_out, int out_size, void* d_ws, size_t ws_size,
                              hipStream_t stream) {
    const float* x    = (const float*)d_in[0];
    const float* comb = (const float*)d_in[1];
    const float* bias = (const float*)d_in[2];
    float* out        = (float*)d_out;

    int nblocks = BB * HH * 2;   // 3600
    flow_mfma_kernel<<<nblocks, 256, 0, stream>>>(x, comb, bias, out);
}

// Round 5
// 33.331 us; speedup vs baseline: 2.1970x; 1.3012x over previous
//
#include <hip/hip_runtime.h>

// 3x3 cross-correlation, padding=1, NCHW, fp32 in/out, bf16 MFMA compute.
// out[b,o,h,w] = bias[o] + sum_{i,c} comb[o, i*16+c] * x[b,c,h+dy_i,w+dx_i]
// B=4, C=16, O=16, H=450, W=480. K = 144 = 9 flows x 16 c, padded to 5x32.
//
// Round 5: granularity. R4 had nothing saturated (HBM 32%, VALU 16%, occ 52%)
// -> latency/granularity bound; each x row staged 3x (one per h-block).
//  - 4-row blocks: stage 6 rows, compute 4 (halo 1.5x, was 3x). 904 blocks.
//  - wave wv owns output row h0+wv (15 tiles x 5 MFMA).
//  - staging loop fully unrolled (11 + tail) -> many loads in flight.
//  - plane-major staging decode -> contiguous LDS writes (no conflicts).
//  - bijective XCD swizzle (904 = 8*113): vertical neighbors share L2.
//  - nontemporal out stores (out is write-once; keep L2 for x halo).

#define HH 450
#define WW 480
#define BB 4
#define CC 16
#define OO 16
#define WT    240                // output pixels per block (width)
#define WIN   244                // staged wi count (w0-1 .. w0+242)
#define RSTG  6                  // staged rows per block
#define ROUT  4                  // output rows per block
#define HG    113                // row-groups: ceil(450/4)
#define NTILE 15                 // 16-pixel MFMA tiles per row
#define ITEMS (2 * RSTG * WIN)   // 2928 staging items
#define HALFI (RSTG * WIN)       // 1464

typedef __attribute__((ext_vector_type(8))) short    bf16x8;
typedef __attribute__((ext_vector_type(4))) float    f32x4;
typedef __attribute__((ext_vector_type(4))) unsigned u32x4;

static __device__ __forceinline__ unsigned cvt_pk_bf16(float a, float b) {
    unsigned r;
    asm("v_cvt_pk_bf16_f32 %0, %1, %2" : "=v"(r) : "v"(a), "v"(b));
    return r;   // lo16 = bf16(a), hi16 = bf16(b), RNE
}

__global__ __launch_bounds__(256, 3) void flow_mfma_kernel(
    const float* __restrict__ x, const float* __restrict__ comb,
    const float* __restrict__ bias, float* __restrict__ out)
{
    // [c-half][r*WIN + wi][8 shorts] : 16B rows, 46848 B total -> 3 blocks/CU
    __shared__ __align__(16) short xs[2][RSTG * WIN][8];

    const int tid  = threadIdx.x;
    const int lane = tid & 63;
    const int wv   = tid >> 6;

    // ---- XCD swizzle: 904 = 8*113 blocks; give each XCD a contiguous
    // logical range so vertically-adjacent row-groups share an L2 ----
    int L    = (blockIdx.x & 7) * HG + (blockIdx.x >> 3);
    int hg   = L % HG;
    int t2   = L / HG;            // b*2 + half
    int half = t2 & 1;
    int b    = t2 >> 1;
    int h0   = hg * ROUT;
    int w0   = half * WT;

    // ---- A-frags: weights fp32->bf16 once, in VGPRs ----
    const int col = lane & 15;          // pixel-in-tile (B col) / output o (A row)
    const int grp = lane >> 4;          // 0..3
    bf16x8 af[5];
    #pragma unroll
    for (int m = 0; m < 5; ++m) {
        int k0 = m * 32 + grp * 8;
        u32x4 p;
        if (k0 < 144) {
            float4 u = *(const float4*)(comb + col * 144 + k0);
            float4 v = *(const float4*)(comb + col * 144 + k0 + 4);
            p[0] = cvt_pk_bf16(u.x, u.y);
            p[1] = cvt_pk_bf16(u.z, u.w);
            p[2] = cvt_pk_bf16(v.x, v.y);
            p[3] = cvt_pk_bf16(v.z, v.w);
        } else {
            p[0] = p[1] = p[2] = p[3] = 0u;
        }
        af[m] = __builtin_bit_cast(bf16x8, p);
    }
    f32x4 bv = *(const f32x4*)(bias + grp * 4);   // acc init: bias[grp*4+r]

    // ---- stage x -> LDS bf16 (plane-major: contiguous lane writes) ----
    auto stage = [&](int s) {
        int ch = (s >= HALFI) ? 1 : 0;
        int r2 = s - ch * HALFI;          // r*WIN + wi
        int r  = r2 / WIN;
        int wi = r2 - r * WIN;
        int hy = h0 - 1 + r;
        int w  = w0 + wi - 1;
        u32x4 p;
        if (((unsigned)hy < (unsigned)HH) && ((unsigned)w < (unsigned)WW)) {
            const float* xp = x + (((size_t)(b * CC + ch * 8) * HH + hy) * WW + w);
            float f0 = xp[0];
            float f1 = xp[(size_t)1 * HH * WW];
            float f2 = xp[(size_t)2 * HH * WW];
            float f3 = xp[(size_t)3 * HH * WW];
            float f4 = xp[(size_t)4 * HH * WW];
            float f5 = xp[(size_t)5 * HH * WW];
            float f6 = xp[(size_t)6 * HH * WW];
            float f7 = xp[(size_t)7 * HH * WW];
            p[0] = cvt_pk_bf16(f0, f1);
            p[1] = cvt_pk_bf16(f2, f3);
            p[2] = cvt_pk_bf16(f4, f5);
            p[3] = cvt_pk_bf16(f6, f7);
        } else {
            p[0] = p[1] = p[2] = p[3] = 0u;
        }
        *(u32x4*)(&xs[ch][r2][0]) = p;
    };
    #pragma unroll
    for (int it = 0; it < 11; ++it)       // 11*256 = 2816 items
        stage(tid + it * 256);
    if (tid < ITEMS - 11 * 256)           // tail: 112 items
        stage(tid + 11 * 256);
    __syncthreads();

    // ---- compute: wave wv owns output row h0 + wv ----
    int h = h0 + wv;
    if (h < HH) {
        // chunk m<4: flow i = 2m + (grp>>1), c-half ch = grp&1
        const int fo = grp >> 1;
        const int ch = grp & 1;
        int boff[5];
        #pragma unroll
        for (int m = 0; m < 4; ++m) {
            int i  = 2 * m + fo;
            int ky = i / 3;
            int kx = i % 3;
            boff[m] = (wv + ky) * WIN + col + kx;
        }
        boff[4] = (wv + 2) * WIN + col + 2;      // flow 8 (ky=2, kx=2)

        for (int t = 0; t < NTILE; ++t) {
            int n0 = t * 16;
            f32x4 acc = bv;
            #pragma unroll
            for (int m = 0; m < 4; ++m) {
                bf16x8 bf = *(const bf16x8*)(&xs[ch][boff[m] + n0][0]);
                acc = __builtin_amdgcn_mfma_f32_16x16x32_bf16(af[m], bf, acc, 0, 0, 0);
            }
            bf16x8 b4;
            if (grp < 2) {
                b4 = *(const bf16x8*)(&xs[ch][boff[4] + n0][0]);
            } else {
                #pragma unroll
                for (int j = 0; j < 8; ++j) b4[j] = 0;
            }
            acc = __builtin_amdgcn_mfma_f32_16x16x32_bf16(af[4], b4, acc, 0, 0, 0);

            // D: col = pixel, row o = grp*4 + r
            float* op = out + (((size_t)(b * OO + grp * 4) * HH + h) * WW + w0 + n0 + col);
            #pragma unroll
            for (int r = 0; r < 4; ++r)
                __builtin_nontemporal_store(acc[r], op + (size_t)r * HH * WW);
        }
    }
}

extern "C" void kernel_launch(void* const* d_in, const int* in_sizes, int n_in,
                              void* d_out, int out_size, void* d_ws, size_t ws_size,
                              hipStream_t stream) {
    const float* x    = (const float*)d_in[0];
    const float* comb = (const float*)d_in[1];
    const float* bias = (const float*)d_in[2];
    float* out        = (float*)d_out;

    int nblocks = BB * 2 * HG;   // 904 = 8 * 113 (bijective XCD swizzle)
    flow_mfma_kernel<<<nblocks, 256, 0, stream>>>(x, comb, bias, out);
}

// Round 6
// 26.378 us; speedup vs baseline: 2.7761x; 1.2636x over previous
//
#include <hip/hip_runtime.h>

// 3x3 cross-correlation, padding=1, NCHW, fp32 in/out, bf16 MFMA compute.
// out[b,o,h,w] = bias[o] + sum_{i,c} comb[o, i*16+c] * x[b,c,h+dy_i,w+dx_i]
// B=4, C=16, O=16, H=450, W=480. K = 144 = 9 flows x 16 c, padded to 5x32.
//
// Round 6 (from R5 counters: WRITE_SIZE 73MB = NT-store amplification;
// occupancy 19.5% = 1.18 scheduling rounds of latency-bound blocks):
//  - normal stores (L2 writeback, full lines)     -> WRITE ~56MB
//  - WT=96 x ROUT=8 tiles: LDS 31.25KB, 5 blocks/CU, grid 1140 <= 1280
//    capacity -> ALL blocks resident, single round, no tail
//  - wave wv computes rows 2wv, 2wv+1 (even split), 6 tiles x 5 MFMA each
//  - bijective XCD swizzle: each XCD gets contiguous vertical strips

#define HH 450
#define WW 480
#define BB 4
#define CC 16
#define OO 16
#define WT    96                 // output pixels per block (width), 6 tiles
#define WQN   5                  // width groups per row
#define WIN   100                // staged wi count (w0-1 .. w0+98)
#define RSTG  10                 // staged rows per block
#define ROUT  8                  // output rows per block
#define HG    57                 // row-groups: ceil(450/8)
#define NTILE 6                  // 16-pixel MFMA tiles per row
#define ITEMS (2 * RSTG * WIN)   // 2000 staging items
#define HALFI (RSTG * WIN)       // 1000
#define NBLK  (BB * WQN * HG)    // 1140

typedef __attribute__((ext_vector_type(8))) short    bf16x8;
typedef __attribute__((ext_vector_type(4))) float    f32x4;
typedef __attribute__((ext_vector_type(4))) unsigned u32x4;

static __device__ __forceinline__ unsigned cvt_pk_bf16(float a, float b) {
    unsigned r;
    asm("v_cvt_pk_bf16_f32 %0, %1, %2" : "=v"(r) : "v"(a), "v"(b));
    return r;   // lo16 = bf16(a), hi16 = bf16(b), RNE
}

__global__ __launch_bounds__(256, 5) void flow_mfma_kernel(
    const float* __restrict__ x, const float* __restrict__ comb,
    const float* __restrict__ bias, float* __restrict__ out)
{
    // [c-half][r*WIN + wi][8 shorts] : 16B rows, 32000 B -> 5 blocks/CU
    __shared__ __align__(16) short xs[2][RSTG * WIN][8];

    const int tid  = threadIdx.x;
    const int lane = tid & 63;
    const int wv   = tid >> 6;

    // ---- bijective XCD swizzle (1140 = 8*142 + 4): xcd gets contiguous
    // logical run -> vertical strip neighbors share an XCD L2 ----
    int bid = blockIdx.x;
    int xcd = bid & 7, pos = bid >> 3;
    int L   = (xcd < 4) ? xcd * 143 + pos : 4 * 143 + (xcd - 4) * 142 + pos;
    // decode: L = ((b*WQN) + wq)*HG + hg   (hg fastest -> strips contiguous)
    int hg  = L % HG;
    int t2  = L / HG;
    int wq  = t2 % WQN;
    int b   = t2 / WQN;
    int h0  = hg * ROUT;
    int w0  = wq * WT;

    // ---- A-frags: weights fp32->bf16 once, in VGPRs ----
    const int col = lane & 15;          // pixel-in-tile (B col) / output o (A row)
    const int grp = lane >> 4;          // 0..3
    bf16x8 af[5];
    #pragma unroll
    for (int m = 0; m < 5; ++m) {
        int k0 = m * 32 + grp * 8;
        u32x4 p;
        if (k0 < 144) {
            float4 u = *(const float4*)(comb + col * 144 + k0);
            float4 v = *(const float4*)(comb + col * 144 + k0 + 4);
            p[0] = cvt_pk_bf16(u.x, u.y);
            p[1] = cvt_pk_bf16(u.z, u.w);
            p[2] = cvt_pk_bf16(v.x, v.y);
            p[3] = cvt_pk_bf16(v.z, v.w);
        } else {
            p[0] = p[1] = p[2] = p[3] = 0u;
        }
        af[m] = __builtin_bit_cast(bf16x8, p);
    }
    f32x4 bv = *(const f32x4*)(bias + grp * 4);   // acc init: bias[grp*4+r]

    // ---- stage x -> LDS bf16 (plane-major: contiguous lane writes) ----
    auto stage = [&](int s) {
        int ch = (s >= HALFI) ? 1 : 0;
        int r2 = s - ch * HALFI;          // r*WIN + wi
        int r  = r2 / WIN;
        int wi = r2 - r * WIN;
        int hy = h0 - 1 + r;
        int w  = w0 + wi - 1;
        u32x4 p;
        if (((unsigned)hy < (unsigned)HH) && ((unsigned)w < (unsigned)WW)) {
            const float* xp = x + (((size_t)(b * CC + ch * 8) * HH + hy) * WW + w);
            float f0 = xp[0];
            float f1 = xp[(size_t)1 * HH * WW];
            float f2 = xp[(size_t)2 * HH * WW];
            float f3 = xp[(size_t)3 * HH * WW];
            float f4 = xp[(size_t)4 * HH * WW];
            float f5 = xp[(size_t)5 * HH * WW];
            float f6 = xp[(size_t)6 * HH * WW];
            float f7 = xp[(size_t)7 * HH * WW];
            p[0] = cvt_pk_bf16(f0, f1);
            p[1] = cvt_pk_bf16(f2, f3);
            p[2] = cvt_pk_bf16(f4, f5);
            p[3] = cvt_pk_bf16(f6, f7);
        } else {
            p[0] = p[1] = p[2] = p[3] = 0u;
        }
        *(u32x4*)(&xs[ch][r2][0]) = p;
    };
    #pragma unroll
    for (int it = 0; it < 7; ++it)        // 7*256 = 1792 items
        stage(tid + it * 256);
    if (tid < ITEMS - 7 * 256)            // tail: 208 items
        stage(tid + 7 * 256);
    __syncthreads();

    // ---- compute: wave wv owns output rows h0 + 2wv, h0 + 2wv + 1 ----
    const int fo = grp >> 1;
    const int ch = grp & 1;
    #pragma unroll
    for (int rr = 0; rr < 2; ++rr) {
        int r = 2 * wv + rr;              // row within group
        int h = h0 + r;
        if (h >= HH) continue;

        int boff[5];
        #pragma unroll
        for (int m = 0; m < 4; ++m) {
            int i  = 2 * m + fo;
            int ky = i / 3;
            int kx = i % 3;
            boff[m] = (r + ky) * WIN + col + kx;
        }
        boff[4] = (r + 2) * WIN + col + 2;      // flow 8 (ky=2, kx=2)

        #pragma unroll
        for (int t = 0; t < NTILE; ++t) {
            int n0 = t * 16;
            f32x4 acc = bv;
            #pragma unroll
            for (int m = 0; m < 4; ++m) {
                bf16x8 bf = *(const bf16x8*)(&xs[ch][boff[m] + n0][0]);
                acc = __builtin_amdgcn_mfma_f32_16x16x32_bf16(af[m], bf, acc, 0, 0, 0);
            }
            bf16x8 b4;
            if (grp < 2) {
                b4 = *(const bf16x8*)(&xs[ch][boff[4] + n0][0]);
            } else {
                #pragma unroll
                for (int j = 0; j < 8; ++j) b4[j] = 0;
            }
            acc = __builtin_amdgcn_mfma_f32_16x16x32_bf16(af[4], b4, acc, 0, 0, 0);

            // D: col = pixel, row o = grp*4 + j
            float* op = out + (((size_t)(b * OO + grp * 4) * HH + h) * WW + w0 + n0 + col);
            #pragma unroll
            for (int j = 0; j < 4; ++j)
                op[(size_t)j * HH * WW] = acc[j];
        }
    }
}

extern "C" void kernel_launch(void* const* d_in, const int* in_sizes, int n_in,
                              void* d_out, int out_size, void* d_ws, size_t ws_size,
                              hipStream_t stream) {
    const float* x    = (const float*)d_in[0];
    const float* comb = (const float*)d_in[1];
    const float* bias = (const float*)d_in[2];
    float* out        = (float*)d_out;

    flow_mfma_kernel<<<NBLK, 256, 0, stream>>>(x, comb, bias, out);
}